// Round 1
// baseline (982.391 us; speedup 1.0000x reference)
//
#include <hip/hip_runtime.h>
#include <cstdint>
#include <cstddef>

#define NN 50000
#define NE 800000
#define NREL 32
#define DIM 128
#define BN_EPS 1e-5f
#define CPB 64            // chunks per relation in main kernel

// ---- workspace layout (units of 4 bytes) ----
// h      : [0,        6400000)   float  N*128 aggregate output
// wmod   : [6400000,  6924288)   float  32*128*128  (edge_feat ⊙ W_R)
// snorm  : [6924288,  7724288)   float  sorted etype_norm
// ssrc   : [7724288,  8524288)   int    sorted src
// sdst   : [8524288,  9324288)   int    sorted dst
// cnt    : [9324288,  9324320)   int    per-relation edge count
// off    : [9324320,  9324353)   int    exclusive scan (33 entries)
// cursor : [9324353,  9324385)   int    scatter cursors
// stats  : [9324385,  9324641)   float  [sum(128) | sumsq(128)]
#define WS_H      0
#define WS_WMOD   6400000
#define WS_SNORM  6924288
#define WS_SSRC   7724288
#define WS_SDST   8524288
#define WS_CNT    9324288
#define WS_OFF    9324320
#define WS_CURSOR 9324353
#define WS_STATS  9324385
#define WS_END    9324641

// ---------- Wmod = edge_feat[r,d] * W_R[r,d,o] ----------
__global__ void k_wmod(const float* __restrict__ ef, const float* __restrict__ WR,
                       float* __restrict__ wmod) {
    int idx = blockIdx.x * 256 + threadIdx.x;          // grid covers 32*128*128 exactly
    int r = idx >> 14;
    int d = (idx >> 7) & 127;
    wmod[idx] = ef[(r << 7) + d] * WR[idx];
}

// ---------- histogram of etype (LDS-aggregated) ----------
__global__ void k_hist(const int* __restrict__ etype, int* __restrict__ cnt) {
    __shared__ int lc[NREL];
    if (threadIdx.x < NREL) lc[threadIdx.x] = 0;
    __syncthreads();
    for (int i = blockIdx.x * blockDim.x + threadIdx.x; i < NE;
         i += gridDim.x * blockDim.x)
        atomicAdd(&lc[etype[i]], 1);
    __syncthreads();
    if (threadIdx.x < NREL) atomicAdd(&cnt[threadIdx.x], lc[threadIdx.x]);
}

// ---------- tiny exclusive scan over 32 bins ----------
__global__ void k_scan(const int* __restrict__ cnt, int* __restrict__ off,
                       int* __restrict__ cursor) {
    if (threadIdx.x == 0) {
        int a = 0;
        for (int r = 0; r < NREL; ++r) {
            off[r] = a; cursor[r] = a; a += cnt[r];
        }
        off[NREL] = a;
    }
}

// ---------- counting-sort scatter (block-reserved ranges) ----------
__global__ void k_scatter(const int* __restrict__ etype, const int* __restrict__ src,
                          const int* __restrict__ dst, const float* __restrict__ norm,
                          int* __restrict__ cursor,
                          int* __restrict__ ssrc, int* __restrict__ sdst,
                          float* __restrict__ snorm) {
    __shared__ int lc[NREL], lbase[NREL];
    int i0 = blockIdx.x * 2048;
    int i1 = min(i0 + 2048, NE);
    if (threadIdx.x < NREL) lc[threadIdx.x] = 0;
    __syncthreads();
    for (int i = i0 + threadIdx.x; i < i1; i += 256)
        atomicAdd(&lc[etype[i]], 1);
    __syncthreads();
    if (threadIdx.x < NREL) {
        lbase[threadIdx.x] = atomicAdd(&cursor[threadIdx.x], lc[threadIdx.x]);
        lc[threadIdx.x] = 0;
    }
    __syncthreads();
    for (int i = i0 + threadIdx.x; i < i1; i += 256) {
        int et = etype[i];
        int pos = lbase[et] + atomicAdd(&lc[et], 1);
        ssrc[pos] = src[i];
        sdst[pos] = dst[i];
        snorm[pos] = norm[i];
    }
}

// ---------- out2 = edge_feat @ W_rel ----------
__global__ void k_out2(const float* __restrict__ ef, const float* __restrict__ wrel,
                       float* __restrict__ out2) {
    int r = blockIdx.x;          // 32 blocks
    int o = threadIdx.x;         // 128 threads
    float y0 = 0.f, y1 = 0.f;
    #pragma unroll
    for (int d = 0; d < DIM; d += 2) {
        y0 = fmaf(ef[r * DIM + d],     wrel[d * DIM + o],       y0);
        y1 = fmaf(ef[r * DIM + d + 1], wrel[(d + 1) * DIM + o], y1);
    }
    out2[r * DIM + o] = y0 + y1;
}

// ---------- main: per-edge matvec with Wmod column in VGPRs ----------
__global__ __launch_bounds__(256, 2)
void k_main(const float* __restrict__ node_feat, const float* __restrict__ wmod,
            const int* __restrict__ ssrc, const int* __restrict__ sdst,
            const float* __restrict__ snorm, const int* __restrict__ off,
            float* __restrict__ h) {
    const int r = blockIdx.x / CPB;
    const int c = blockIdx.x % CPB;
    const int t = threadIdx.x;
    const int o = t & 127;       // output column owned by this thread
    const int pair = t >> 7;     // wave-uniform: waves 0,1 -> 0; waves 2,3 -> 1

    const int beg = off[r], end = off[r + 1];
    const int cnt = end - beg;
    const int L = (cnt + CPB - 1) / CPB;
    const int s = beg + c * L;
    const int e_end = min(s + L, end);

    // load this thread's Wmod column into registers (static indexing)
    float w[DIM];
    const float* wr = wmod + ((size_t)r << 14);
    #pragma unroll
    for (int d = 0; d < DIM; ++d) w[d] = wr[d * DIM + o];

    for (int e = s + pair; e < e_end; e += 2) {
        int   src  = __builtin_amdgcn_readfirstlane(ssrc[e]);
        int   dst  = sdst[e];
        float norm = snorm[e];
        const float* xp = node_feat + ((size_t)src << 7);  // wave-uniform -> s_load
        float y0 = 0.f, y1 = 0.f, y2 = 0.f, y3 = 0.f;
        #pragma unroll
        for (int d = 0; d < DIM; d += 4) {
            y0 = fmaf(xp[d],     w[d],     y0);
            y1 = fmaf(xp[d + 1], w[d + 1], y1);
            y2 = fmaf(xp[d + 2], w[d + 2], y2);
            y3 = fmaf(xp[d + 3], w[d + 3], y3);
        }
        float y = ((y0 + y1) + (y2 + y3)) * norm;
        atomicAdd(&h[((size_t)dst << 7) + o], y);
    }
}

// ---------- BatchNorm stats: per-channel sum / sumsq ----------
__global__ void k_bnstat(const float* __restrict__ h, float* __restrict__ stats) {
    const int t = threadIdx.x;
    const int o = t & 127;
    const int half = t >> 7;
    float s = 0.f, ss = 0.f;
    for (int n = blockIdx.x * 2 + half; n < NN; n += gridDim.x * 2) {
        float v = h[(size_t)n * DIM + o];
        s += v; ss += v * v;
    }
    __shared__ float bs[256], bss[256];
    bs[t] = s; bss[t] = ss;
    __syncthreads();
    if (t < 128) {
        atomicAdd(&stats[o],       bs[t] + bs[t + 128]);
        atomicAdd(&stats[128 + o], bss[t] + bss[t + 128]);
    }
}

// ---------- BatchNorm apply + tanh ----------
__global__ void k_bnapply(const float* __restrict__ h, const float* __restrict__ stats,
                          const float* __restrict__ gamma, const float* __restrict__ beta,
                          float* __restrict__ out) {
    const float invN = 1.f / (float)NN;
    for (int idx = blockIdx.x * 256 + threadIdx.x; idx < NN * DIM;
         idx += gridDim.x * 256) {
        int o = idx & 127;
        float mean = stats[o] * invN;
        float var  = stats[128 + o] * invN - mean * mean;
        float v = (h[idx] - mean) * rsqrtf(var + BN_EPS) * gamma[o] + beta[o];
        out[idx] = tanhf(v);
    }
}

extern "C" void kernel_launch(void* const* d_in, const int* in_sizes, int n_in,
                              void* d_out, int out_size, void* d_ws, size_t ws_size,
                              hipStream_t stream) {
    const float* node_feat = (const float*)d_in[0];
    const float* edge_feat = (const float*)d_in[1];
    const float* W_R       = (const float*)d_in[2];
    const float* W_rel     = (const float*)d_in[3];
    const float* bn_gamma  = (const float*)d_in[4];
    const float* bn_beta   = (const float*)d_in[5];
    const float* enorm     = (const float*)d_in[6];
    const int*   src       = (const int*)d_in[7];
    const int*   dst       = (const int*)d_in[8];
    const int*   etype     = (const int*)d_in[9];

    float* ws_f = (float*)d_ws;
    int*   ws_i = (int*)d_ws;

    float* h      = ws_f + WS_H;
    float* wmod   = ws_f + WS_WMOD;
    float* snorm  = ws_f + WS_SNORM;
    int*   ssrc   = ws_i + WS_SSRC;
    int*   sdst   = ws_i + WS_SDST;
    int*   cnt    = ws_i + WS_CNT;
    int*   off    = ws_i + WS_OFF;
    int*   cursor = ws_i + WS_CURSOR;
    float* stats  = ws_f + WS_STATS;

    float* out_h  = (float*)d_out;              // N*128
    float* out2   = (float*)d_out + NN * DIM;   // 32*128

    // zero h and the small tail (cnt..stats); ws is poisoned 0xAA each call
    hipMemsetAsync(h, 0, (size_t)NN * DIM * sizeof(float), stream);
    hipMemsetAsync(ws_i + WS_CNT, 0, (WS_END - WS_CNT) * sizeof(int), stream);

    k_wmod    <<<2048, 256, 0, stream>>>(edge_feat, W_R, wmod);
    k_hist    <<<256, 256, 0, stream>>>(etype, cnt);
    k_scan    <<<1, 64, 0, stream>>>(cnt, off, cursor);
    k_scatter <<<(NE + 2047) / 2048, 256, 0, stream>>>(etype, src, dst, enorm,
                                                       cursor, ssrc, sdst, snorm);
    k_out2    <<<NREL, DIM, 0, stream>>>(edge_feat, W_rel, out2);
    k_main    <<<NREL * CPB, 256, 0, stream>>>(node_feat, wmod, ssrc, sdst, snorm,
                                               off, h);
    k_bnstat  <<<512, 256, 0, stream>>>(h, stats);
    k_bnapply <<<2048, 256, 0, stream>>>(h, stats, bn_gamma, bn_beta, out_h);
}